// Round 6
// baseline (1067.015 us; speedup 1.0000x reference)
//
#include <hip/hip_runtime.h>
#include <math.h>

// ---------------- constants ----------------
#define T_STEPS 50
#define NB 512
#define RS2 0.70710678118654752f
#define INV_SQRT_L 0.40824829046386302f
#define WPACK_SHORT_OFF 36864    // d_ws offset in shorts (= float off 18432)

struct SchedArg { float cx0[T_STEPS], cxt[T_STEPS], sig[T_STEPS], s1m[T_STEPS], isab[T_STEPS]; };
struct FreqArg  { double f[64]; };

typedef short bf16x8 __attribute__((ext_vector_type(8)));
typedef float f32x4  __attribute__((ext_vector_type(4)));

__device__ __forceinline__ float4 ld4s(const float* p) { return *reinterpret_cast<const float4*>(p); }
__device__ __forceinline__ void   st4s(float* p, float4 v) { *reinterpret_cast<float4*>(p) = v; }
__device__ __forceinline__ float4 ld4g(const float* __restrict__ p) { return *reinterpret_cast<const float4*>(p); }
__device__ __forceinline__ float fast_sig(float x)  { return 1.f / (1.f + __expf(-x)); }
__device__ __forceinline__ float fast_tanh(float x) { float e = __expf(2.f * x); return 1.f - 2.f / (e + 1.f); }

__device__ __forceinline__ unsigned rne1(float f) {          // f32 -> bf16 bits (RNE)
    unsigned u = __float_as_uint(f);
    return (u + 0x7FFFu + ((u >> 16) & 1u)) >> 16;
}
__device__ __forceinline__ unsigned pk2(float a, float b) {
    return (rne1(a) & 0xFFFFu) | (rne1(b) << 16);
}
__device__ __forceinline__ void st_bf4(short* p, float a, float b, float c, float d) {
    uint2 v; v.x = pk2(a, b); v.y = pk2(c, d);
    *reinterpret_cast<uint2*>(p) = v;
}
__device__ __forceinline__ float bf2f(unsigned hi16) {
    return __uint_as_float(hi16 << 16);
}
__device__ __forceinline__ f32x4 mma(bf16x8 a, bf16x8 b, f32x4 c) {
    return __builtin_amdgcn_mfma_f32_16x16x32_bf16(a, b, c, 0, 0, 0);
}
__device__ __forceinline__ f32x4 bias4(const float* __restrict__ p) {
    float4 b = ld4g(p);
    f32x4 r; r[0] = b.x; r[1] = b.y; r[2] = b.z; r[3] = b.w;
    return r;
}
__device__ __forceinline__ bf16x8 ldfrag(const short* p) {
    return *reinterpret_cast<const bf16x8*>(p);
}

// ---------------- kernel A: Student-t marginal fit ----------------
__global__ __launch_bounds__(256) void fit_kernel(const float* __restrict__ xh,
                                                  float* __restrict__ loc,
                                                  float* __restrict__ scalef) {
    int gid = blockIdx.x * 256 + threadIdx.x;
    int b = gid >> 7, d = gid & 127;
    const float* p = xh + (size_t)b * 192 * 128 + d;
    float s = 0.f;
    for (int t = 0; t < 192; ++t) s += p[t * 128];
    float m = s * (1.0f / 192.0f);
    float v = 0.f;
    for (int t = 0; t < 192; ++t) {
        float c = p[t * 128] - m; c *= c;
        v = (t == 0) ? c : 0.94f * v + (1.0f - 0.94f) * c;
    }
    loc[gid] = m;
    scalef[gid] = fmaxf(sqrtf(v * 0.5f), 1e-5f);
}

// ---------------- kernel B: per-t embedding -> cond[6][32] ----------------
__global__ __launch_bounds__(256) void temb_kernel(
    const float* __restrict__ w1, const float* __restrict__ b1,
    const float* __restrict__ w2, const float* __restrict__ b2,
    const float* __restrict__ wt, const float* __restrict__ bt,
    float* __restrict__ cond_all, FreqArg fq) {
    int t = blockIdx.x;
    int tid = threadIdx.x;
    __shared__ float pe[128], te1[512], te2[512];
    if (tid < 64) {
        double e = (double)t * fq.f[tid];
        pe[tid]      = (float)sin(e);
        pe[tid + 64] = (float)cos(e);
    }
    __syncthreads();
    for (int j = tid; j < 512; j += 256) {
        float acc = b1[j];
        for (int k = 0; k < 128; ++k) acc += pe[k] * w1[k * 512 + j];
        te1[j] = acc / (1.f + expf(-acc));
    }
    __syncthreads();
    for (int j = tid; j < 512; j += 256) {
        float acc = b2[j];
        for (int k = 0; k < 512; ++k) acc += te1[k] * w2[k * 512 + j];
        te2[j] = acc / (1.f + expf(-acc));
    }
    __syncthreads();
    if (tid < 192) {
        int l = tid >> 5, c = tid & 31;
        float acc = bt[l * 32 + c];
        const float* w = wt + (size_t)l * 512 * 32 + c;
        for (int k = 0; k < 512; ++k) acc += te2[k] * w[k * 32];
        cond_all[t * 192 + tid] = acc;
    }
}

// ---------------- kernel P: pack weights as bf16 A-fragments ----------------
// A-frag layout (v_mfma_f32_16x16x32_bf16): lane l elem j holds A[m=l&15][k=(l>>4)*8+j].
__global__ __launch_bounds__(256) void prep_kernel(
    const float* __restrict__ w_in, const float* __restrict__ lyr_wdil,
    const float* __restrict__ lyr_wout, const float* __restrict__ w_o1,
    const float* __restrict__ w_o2, short* __restrict__ wpack) {
    int gid = blockIdx.x * 256 + threadIdx.x;
    if (gid >= 58368) return;
    int j = gid & 7, l = (gid >> 3) & 63, frag = gid >> 9;
    int m = l & 15, k = (l >> 4) * 8 + j;
    float v;
    if (frag < 8) {
        int m2 = frag >> 2, ks = frag & 3;
        v = w_in[(m2 * 16 + m) * 128 + ks * 32 + k];
    } else if (frag < 80) {
        int fi = frag - 8;
        int li = fi / 12, rem = fi % 12;
        int mg = rem / 6, rem2 = rem % 6;
        int tp = rem2 >> 1, gf = rem2 & 1;
        int o = gf * 32 + mg * 16 + m;
        v = lyr_wdil[((li * 64 + o) * 32 + k) * 3 + tp];
    } else if (frag < 104) {
        int fi = frag - 80;
        int li = fi >> 2, mo = fi & 3;
        v = lyr_wout[li * 2048 + (mo * 16 + m) * 32 + k];
    } else if (frag < 106) {
        int m2 = frag - 104;
        v = w_o1[(m2 * 16 + m) * 32 + k] * INV_SQRT_L;
    } else {
        int m8 = frag - 106;
        v = w_o2[(m8 * 16 + m) * 32 + k];
    }
    wpack[gid] = (short)rne1(v);
}

// ---------------- kernel C: 50-step diffusion (MFMA), 1 row/block, 2 blocks/CU ----------------
// cols: 0..23 valid h, tiles n in {0,1} (cols 24..31 pad, never stored).
__global__ __launch_bounds__(256, 2) void diffusion_kernel(
    const float* __restrict__ z_init, const float* __restrict__ noise,
    const float* __restrict__ b_in,  const float* __restrict__ lyr_bdil,
    const float* __restrict__ lyr_bout, const float* __restrict__ b_o1,
    const float* __restrict__ b_o2, const float* __restrict__ cond_all,
    const short* __restrict__ wpack, const float* __restrict__ loc,
    const float* __restrict__ scalef, float* __restrict__ out, SchedArg sc) {

    __shared__ __align__(16) float xsf[24 * 132];   // x state f32 [h][128d] (pad 132)
    __shared__ __align__(16) short xbB[32 * 136];   // x bf16 [col][128k] (rows 24..31 zero)
    __shared__ __align__(16) short hB [24 * 40];    // h bf16 [col][32c]
    __shared__ __align__(16) short hcB[33 * 40];    // h+cond; col 32 = zeros
    __shared__ __align__(16) short actB[32 * 40];   // conv act / s
    __shared__ __align__(16) short skB[32 * 40];    // skip accumulator

    const int tid = threadIdx.x;
    const int wv  = __builtin_amdgcn_readfirstlane(tid >> 6);   // 0..3
    const int l   = tid & 63;
    const int ln  = l & 15;
    const int lq  = l >> 4;
    const int bb  = blockIdx.x;          // row 0..511

    const short* wpP1 = wpack;
    const short* wpCv = wpack + 4096;
    const short* wpWo = wpack + 40960;
    const short* wpO1 = wpack + 53248;
    const short* wpO2 = wpack + 54272;

    const int m2 = wv >> 1;              // P1 / o1 m-tile
    const int nn = wv & 1;               // P1 / conv / o1 n-tile
    const int colw = nn * 16 + ln;       // this wave's column for 2x2-tiled phases
    const bool cvw = (colw < 24);

    // ---- hoisted step-invariant A-frags ----
    bf16x8 aP1[4], aO1, aO2[2];
#pragma unroll
    for (int ks = 0; ks < 4; ++ks) aP1[ks] = ldfrag(wpP1 + (m2 * 4 + ks) * 512 + l * 8);
    aO1 = ldfrag(wpO1 + m2 * 512 + l * 8);
    aO2[0] = ldfrag(wpO2 + wv * 512 + l * 8);
    aO2[1] = ldfrag(wpO2 + (wv + 4) * 512 + l * 8);

    // ---- init ----
    for (int i = tid; i < 3072; i += 256) {
        int d = i / 24, h = i - d * 24;
        float v = z_init[(size_t)bb * 3072 + i];
        xsf[h * 132 + d] = v;
        xbB[h * 136 + d] = (short)rne1(v);
    }
    for (int i = tid; i < 8 * 136; i += 256) xbB[24 * 136 + i] = 0;   // pad rows
    if (tid < 40) hcB[32 * 40 + tid] = 0;                             // zero col
    for (int i = tid; i < 480; i += 256) reinterpret_cast<unsigned*>(skB)[i] = 0u;
    __syncthreads();

    for (int step = 0; step < T_STEPS; ++step) {
        const int t = T_STEPS - 1 - step;
        const float* cndt = cond_all + t * 192;

        // ---- noise prefetch (consumed at o2) ----
        // At o2 every wave computes n=0 (col=ln) and n=1 (col=16+ln).
        float nzr[2][2][4];
        {
            const float* nzb = noise + ((size_t)step * NB + bb) * 3072;
            const int cc1 = (16 + ln) < 24 ? (16 + ln) : 0;   // n=1 col (clamped; result discarded)
#pragma unroll
            for (int mi = 0; mi < 2; ++mi) {
                const int d0 = (wv + 4 * mi) * 16 + lq * 4;
#pragma unroll
                for (int i = 0; i < 4; ++i) {
                    nzr[mi][0][i] = nzb[(d0 + i) * 24 + ln];   // n=0 col = ln (always valid)
                    nzr[mi][1][i] = nzb[(d0 + i) * 24 + cc1];
                }
            }
        }

        // ======== P1: h = relu(Win @ x + b_in) ========
        {
            f32x4 acc = bias4(b_in + m2 * 16 + lq * 4);
            const short* xb = xbB + colw * 136 + lq * 8;
#pragma unroll
            for (int ks = 0; ks < 4; ++ks)
                acc = mma(aP1[ks], ldfrag(xb + ks * 32), acc);
            if (cvw) {
                float4 cv = ld4g(cndt + m2 * 16 + lq * 4);
                float h0 = fmaxf(acc[0], 0.f), h1 = fmaxf(acc[1], 0.f);
                float h2 = fmaxf(acc[2], 0.f), h3 = fmaxf(acc[3], 0.f);
                st_bf4(hB + colw * 40 + m2 * 16 + lq * 4, h0, h1, h2, h3);
                st_bf4(hcB + colw * 40 + m2 * 16 + lq * 4,
                       h0 + cv.x, h1 + cv.y, h2 + cv.z, h3 + cv.w);
            }
        }
        __syncthreads();

        // ======== 6 residual layers ========
#pragma unroll
        for (int li = 0; li < 6; ++li) {
            const int d = 1 << li;
            // ---- conv (3 shifted K=32 GEMMs) + gated act ----
            {
                const int mg = m2;
                f32x4 accg = bias4(lyr_bdil + li * 64 + mg * 16 + lq * 4);
                f32x4 accf = bias4(lyr_bdil + li * 64 + 32 + mg * 16 + lq * 4);
                const short* wc = wpCv + (li * 12 + mg * 6) * 512 + l * 8;
#pragma unroll
                for (int tp = 0; tp < 3; ++tp) {
                    if (li == 5 && tp != 1) continue;
                    int hh = colw + (tp - 1) * d;
                    int colp = ((unsigned)hh < 24u) ? hh : 32;
                    bf16x8 b = ldfrag(hcB + colp * 40 + lq * 8);
                    accg = mma(ldfrag(wc + (tp * 2 + 0) * 512), b, accg);
                    accf = mma(ldfrag(wc + (tp * 2 + 1) * 512), b, accf);
                }
                if (cvw)
                    st_bf4(actB + colw * 40 + mg * 16 + lq * 4,
                           fast_tanh(accf[0]) * fast_sig(accg[0]),
                           fast_tanh(accf[1]) * fast_sig(accg[1]),
                           fast_tanh(accf[2]) * fast_sig(accg[2]),
                           fast_tanh(accf[3]) * fast_sig(accg[3]));
            }
            __syncthreads();

            // ---- wout: 8 tiles (mo=wv, n=0..1) ----
            {
                const int mo = wv;
                bf16x8 a = ldfrag(wpWo + (li * 4 + mo) * 512 + l * 8);
                f32x4 bia = bias4(lyr_bout + li * 64 + mo * 16 + lq * 4);
#pragma unroll
                for (int n = 0; n < 2; ++n) {
                    const int col = n * 16 + ln;
                    f32x4 acc = mma(a, ldfrag(actB + col * 40 + lq * 8), bia);
                    if (col < 24) {
                        if (mo < 2) {
                            short* hp = hB + col * 40 + mo * 16 + lq * 4;
                            uint2 hv = *reinterpret_cast<uint2*>(hp);
                            float n0 = (bf2f(hv.x & 0xFFFFu) + acc[0]) * RS2;
                            float n1 = (bf2f(hv.x >> 16)     + acc[1]) * RS2;
                            float n2 = (bf2f(hv.y & 0xFFFFu) + acc[2]) * RS2;
                            float n3 = (bf2f(hv.y >> 16)     + acc[3]) * RS2;
                            st_bf4(hp, n0, n1, n2, n3);
                            if (li < 5) {
                                float4 cv = ld4g(cndt + (li + 1) * 32 + mo * 16 + lq * 4);
                                st_bf4(hcB + col * 40 + mo * 16 + lq * 4,
                                       n0 + cv.x, n1 + cv.y, n2 + cv.z, n3 + cv.w);
                            }
                        } else {
                            short* sp = skB + col * 40 + (mo - 2) * 16 + lq * 4;
                            uint2 sv = *reinterpret_cast<uint2*>(sp);
                            st_bf4(sp,
                                   bf2f(sv.x & 0xFFFFu) + acc[0],
                                   bf2f(sv.x >> 16)     + acc[1],
                                   bf2f(sv.y & 0xFFFFu) + acc[2],
                                   bf2f(sv.y >> 16)     + acc[3]);
                        }
                    }
                }
            }
            __syncthreads();
        }

        // ======== o1: s = relu(b_o1 + Wo1s @ skip) -> actB ========
        {
            f32x4 acc = bias4(b_o1 + m2 * 16 + lq * 4);
            acc = mma(aO1, ldfrag(skB + colw * 40 + lq * 8), acc);
            if (cvw)
                st_bf4(actB + colw * 40 + m2 * 16 + lq * 4,
                       fmaxf(acc[0], 0.f), fmaxf(acc[1], 0.f),
                       fmaxf(acc[2], 0.f), fmaxf(acc[3], 0.f));
        }
        __syncthreads();

        // ======== o2: eps + fused DDPM x-update; re-zero skB ========
        {
            const float cx0 = sc.cx0[t], cxt = sc.cxt[t], sig = sc.sig[t];
            const float s1m = sc.s1m[t], isab = sc.isab[t];
#pragma unroll
            for (int mi = 0; mi < 2; ++mi) {
                const int m8 = wv + 4 * mi;
                const int d0 = m8 * 16 + lq * 4;
                f32x4 bia = bias4(b_o2 + d0);
#pragma unroll
                for (int n = 0; n < 2; ++n) {
                    const int col = n * 16 + ln;
                    f32x4 acc = mma(aO2[mi], ldfrag(actB + col * 40 + lq * 8), bia);
                    if (col < 24) {
                        float* xp = xsf + col * 132 + d0;
                        float4 xv = ld4s(xp);
                        float4 rr;
#pragma unroll
                        for (int i = 0; i < 4; ++i) {
                            float xvv = (&xv.x)[i];
                            float nz = nzr[mi][n][i];
                            float x0 = fminf(fmaxf((xvv - s1m * acc[i]) * isab, -1.f), 1.f);
                            (&rr.x)[i] = cx0 * x0 + cxt * xvv + sig * nz;
                        }
                        st4s(xp, rr);
                        st_bf4(xbB + col * 136 + d0, rr.x, rr.y, rr.z, rr.w);
                    }
                }
            }
            for (int i = tid; i < 480; i += 256) reinterpret_cast<unsigned*>(skB)[i] = 0u;
        }
        __syncthreads();
    }

    // ---- epilogue: Gaussian -> Student-t4, coalesced writes ----
    {
        const int b = bb & 31;
        for (int i = tid; i < 768; i += 256) {
            int col = i >> 5, q = i & 31;
            float4 zv = ld4s(xsf + col * 132 + q * 4);
            float4 l4 = ld4g(loc + b * 128 + q * 4);
            float4 s4 = ld4g(scalef + b * 128 + q * 4);
            float4 o4;
#pragma unroll
            for (int e = 0; e < 4; ++e) {
                float u = 0.5f * (1.f + erff((&zv.x)[e] * RS2));
                u = fminf(fmaxf(u, 1e-6f), 1.f - 1e-6f);
                float a4 = fminf(fmaxf(4.f * u * (1.f - u), 1e-12f), 1.f);
                float rr = sqrtf(a4);
                float q2 = 2.f * sqrtf(fmaxf(cosf(acosf(rr) * (1.f / 3.f)) / rr - 1.f, 0.f));
                float tstd = (u < 0.5f) ? -q2 : q2;
                (&o4.x)[e] = (&l4.x)[e] + (&s4.x)[e] * tstd;
            }
            *reinterpret_cast<float4*>(out + ((size_t)bb * 24 + col) * 128 + q * 4) = o4;
        }
    }
}

// ---------------- host ----------------
extern "C" void kernel_launch(void* const* d_in, const int* in_sizes, int n_in,
                              void* d_out, int out_size, void* d_ws, size_t ws_size,
                              hipStream_t stream) {
    const float* x_hist  = (const float*)d_in[0];
    const float* z_init  = (const float*)d_in[1];
    const float* noise   = (const float*)d_in[2];
    const float* w_in    = (const float*)d_in[3];
    const float* b_in    = (const float*)d_in[4];
    const float* temb_w1 = (const float*)d_in[5];
    const float* temb_b1 = (const float*)d_in[6];
    const float* temb_w2 = (const float*)d_in[7];
    const float* temb_b2 = (const float*)d_in[8];
    const float* lyr_wt  = (const float*)d_in[9];
    const float* lyr_bt  = (const float*)d_in[10];
    const float* lyr_wdil= (const float*)d_in[11];
    const float* lyr_bdil= (const float*)d_in[12];
    const float* lyr_wout= (const float*)d_in[13];
    const float* lyr_bout= (const float*)d_in[14];
    const float* w_o1    = (const float*)d_in[15];
    const float* b_o1    = (const float*)d_in[16];
    const float* w_o2    = (const float*)d_in[17];
    const float* b_o2    = (const float*)d_in[18];
    float* out = (float*)d_out;

    float* loc      = (float*)d_ws;                     // 4096 f32
    float* scalef   = loc + 4096;                       // 4096 f32
    float* cond_all = scalef + 4096;                    // 9600 f32
    short* wpack    = (short*)d_ws + WPACK_SHORT_OFF;   // 58368 bf16

    SchedArg sa;
    double abar = 1.0;
    for (int t = 0; t < T_STEPS; ++t) {
        double beta  = 1e-4 + (0.1 - 1e-4) * ((double)t / 49.0);
        double alpha = 1.0 - beta;
        double abprev = abar;
        abar *= alpha;
        sa.cx0[t]  = (float)(beta * sqrt(abprev) / (1.0 - abar));
        sa.cxt[t]  = (float)((1.0 - abprev) * sqrt(alpha) / (1.0 - abar));
        double pv  = beta * (1.0 - abprev) / (1.0 - abar);
        sa.sig[t]  = (t > 0) ? (float)sqrt(pv) : 0.f;
        sa.s1m[t]  = (float)sqrt(1.0 - abar);
        sa.isab[t] = (float)(1.0 / sqrt(abar));
    }
    FreqArg fa;
    for (int j = 0; j < 64; ++j) fa.f[j] = pow(10.0, (double)j * 4.0 / 63.0);

    prep_kernel<<<228, 256, 0, stream>>>(w_in, lyr_wdil, lyr_wout, w_o1, w_o2, wpack);
    fit_kernel<<<16, 256, 0, stream>>>(x_hist, loc, scalef);
    temb_kernel<<<T_STEPS, 256, 0, stream>>>(temb_w1, temb_b1, temb_w2, temb_b2,
                                             lyr_wt, lyr_bt, cond_all, fa);
    diffusion_kernel<<<NB, 256, 0, stream>>>(z_init, noise, b_in, lyr_bdil,
                                             lyr_bout, b_o1, b_o2, cond_all,
                                             wpack, loc, scalef, out, sa);
}

// Round 7
// 960.013 us; speedup vs baseline: 1.1115x; 1.1115x over previous
//
#include <hip/hip_runtime.h>
#include <math.h>

// ---------------- constants ----------------
#define T_STEPS 50
#define NB 512
#define RS2 0.70710678118654752f
#define INV_SQRT_L 0.40824829046386302f
#define WPACK_SHORT_OFF 36864    // d_ws offset in shorts (= float off 18432)

struct SchedArg { float cx0[T_STEPS], cxt[T_STEPS], sig[T_STEPS], s1m[T_STEPS], isab[T_STEPS]; };
struct FreqArg  { double f[64]; };

typedef short bf16x8 __attribute__((ext_vector_type(8)));
typedef float f32x4  __attribute__((ext_vector_type(4)));

__device__ __forceinline__ float4 ld4s(const float* p) { return *reinterpret_cast<const float4*>(p); }
__device__ __forceinline__ void   st4s(float* p, float4 v) { *reinterpret_cast<float4*>(p) = v; }
__device__ __forceinline__ float4 ld4g(const float* __restrict__ p) { return *reinterpret_cast<const float4*>(p); }
__device__ __forceinline__ float fast_sig(float x)  { return 1.f / (1.f + __expf(-x)); }
__device__ __forceinline__ float fast_tanh(float x) { float e = __expf(2.f * x); return 1.f - 2.f / (e + 1.f); }

__device__ __forceinline__ unsigned rne1(float f) {          // f32 -> bf16 bits (RNE)
    unsigned u = __float_as_uint(f);
    return (u + 0x7FFFu + ((u >> 16) & 1u)) >> 16;
}
__device__ __forceinline__ unsigned pk2(float a, float b) {
    return (rne1(a) & 0xFFFFu) | (rne1(b) << 16);
}
__device__ __forceinline__ void st_bf4(short* p, float a, float b, float c, float d) {
    uint2 v; v.x = pk2(a, b); v.y = pk2(c, d);
    *reinterpret_cast<uint2*>(p) = v;
}
__device__ __forceinline__ float bf2f(unsigned hi16) {
    return __uint_as_float(hi16 << 16);
}
__device__ __forceinline__ f32x4 mma(bf16x8 a, bf16x8 b, f32x4 c) {
    return __builtin_amdgcn_mfma_f32_16x16x32_bf16(a, b, c, 0, 0, 0);
}
__device__ __forceinline__ f32x4 bias4(const float* __restrict__ p) {
    float4 b = ld4g(p);
    f32x4 r; r[0] = b.x; r[1] = b.y; r[2] = b.z; r[3] = b.w;
    return r;
}
__device__ __forceinline__ bf16x8 ldfrag(const short* p) {
    return *reinterpret_cast<const bf16x8*>(p);
}

// ---------------- kernel A: Student-t marginal fit ----------------
__global__ __launch_bounds__(256) void fit_kernel(const float* __restrict__ xh,
                                                  float* __restrict__ loc,
                                                  float* __restrict__ scalef) {
    int gid = blockIdx.x * 256 + threadIdx.x;
    int b = gid >> 7, d = gid & 127;
    const float* p = xh + (size_t)b * 192 * 128 + d;
    float s = 0.f;
    for (int t = 0; t < 192; ++t) s += p[t * 128];
    float m = s * (1.0f / 192.0f);
    float v = 0.f;
    for (int t = 0; t < 192; ++t) {
        float c = p[t * 128] - m; c *= c;
        v = (t == 0) ? c : 0.94f * v + (1.0f - 0.94f) * c;
    }
    loc[gid] = m;
    scalef[gid] = fmaxf(sqrtf(v * 0.5f), 1e-5f);
}

// ---------------- kernel B: per-t embedding -> cond[6][32] ----------------
__global__ __launch_bounds__(256) void temb_kernel(
    const float* __restrict__ w1, const float* __restrict__ b1,
    const float* __restrict__ w2, const float* __restrict__ b2,
    const float* __restrict__ wt, const float* __restrict__ bt,
    float* __restrict__ cond_all, FreqArg fq) {
    int t = blockIdx.x;
    int tid = threadIdx.x;
    __shared__ float pe[128], te1[512], te2[512];
    if (tid < 64) {
        double e = (double)t * fq.f[tid];
        pe[tid]      = (float)sin(e);
        pe[tid + 64] = (float)cos(e);
    }
    __syncthreads();
    for (int j = tid; j < 512; j += 256) {
        float acc = b1[j];
        for (int k = 0; k < 128; ++k) acc += pe[k] * w1[k * 512 + j];
        te1[j] = acc / (1.f + expf(-acc));
    }
    __syncthreads();
    for (int j = tid; j < 512; j += 256) {
        float acc = b2[j];
        for (int k = 0; k < 512; ++k) acc += te1[k] * w2[k * 512 + j];
        te2[j] = acc / (1.f + expf(-acc));
    }
    __syncthreads();
    if (tid < 192) {
        int l = tid >> 5, c = tid & 31;
        float acc = bt[l * 32 + c];
        const float* w = wt + (size_t)l * 512 * 32 + c;
        for (int k = 0; k < 512; ++k) acc += te2[k] * w[k * 32];
        cond_all[t * 192 + tid] = acc;
    }
}

// ---------------- kernel P: pack weights as bf16 A-fragments ----------------
// A-frag layout (v_mfma_f32_16x16x32_bf16): lane l elem j holds A[m=l&15][k=(l>>4)*8+j].
__global__ __launch_bounds__(256) void prep_kernel(
    const float* __restrict__ w_in, const float* __restrict__ lyr_wdil,
    const float* __restrict__ lyr_wout, const float* __restrict__ w_o1,
    const float* __restrict__ w_o2, short* __restrict__ wpack) {
    int gid = blockIdx.x * 256 + threadIdx.x;
    if (gid >= 58368) return;
    int j = gid & 7, l = (gid >> 3) & 63, frag = gid >> 9;
    int m = l & 15, k = (l >> 4) * 8 + j;
    float v;
    if (frag < 8) {
        int m2 = frag >> 2, ks = frag & 3;
        v = w_in[(m2 * 16 + m) * 128 + ks * 32 + k];
    } else if (frag < 80) {
        int fi = frag - 8;
        int li = fi / 12, rem = fi % 12;
        int mg = rem / 6, rem2 = rem % 6;
        int tp = rem2 >> 1, gf = rem2 & 1;
        int o = gf * 32 + mg * 16 + m;
        v = lyr_wdil[((li * 64 + o) * 32 + k) * 3 + tp];
    } else if (frag < 104) {
        int fi = frag - 80;
        int li = fi >> 2, mo = fi & 3;
        v = lyr_wout[li * 2048 + (mo * 16 + m) * 32 + k];
    } else if (frag < 106) {
        int m2 = frag - 104;
        v = w_o1[(m2 * 16 + m) * 32 + k] * INV_SQRT_L;
    } else {
        int m8 = frag - 106;
        v = w_o2[(m8 * 16 + m) * 32 + k];
    }
    wpack[gid] = (short)rne1(v);
}

// ---------------- kernel C: 50-step diffusion (MFMA), 1 row/block, 2 blocks/CU ----------------
// cols: 0..23 valid h, tiles n in {0,1} (cols 24..31 pad, never stored).
// Noise: staged coalesced (global float4 loads at step start -> LDS write at end
// of P1 -> scattered reads at o2 from LDS). T14 async-split: HBM latency hides
// under P1's MFMA chain.
__global__ __launch_bounds__(256, 2) void diffusion_kernel(
    const float* __restrict__ z_init, const float* __restrict__ noise,
    const float* __restrict__ b_in,  const float* __restrict__ lyr_bdil,
    const float* __restrict__ lyr_bout, const float* __restrict__ b_o1,
    const float* __restrict__ b_o2, const float* __restrict__ cond_all,
    const short* __restrict__ wpack, const float* __restrict__ loc,
    const float* __restrict__ scalef, float* __restrict__ out, SchedArg sc) {

    __shared__ __align__(16) float xsf[24 * 132];   // x state f32 [h][128d] (pad 132)
    __shared__ __align__(16) float nzB[3072];       // this step's noise [128d][24h]
    __shared__ __align__(16) short xbB[32 * 136];   // x bf16 [col][128k] (rows 24..31 zero)
    __shared__ __align__(16) short hB [24 * 40];    // h bf16 [col][32c]
    __shared__ __align__(16) short hcB[33 * 40];    // h+cond; col 32 = zeros
    __shared__ __align__(16) short actB[32 * 40];   // conv act / s
    __shared__ __align__(16) short skB[32 * 40];    // skip accumulator

    const int tid = threadIdx.x;
    const int wv  = __builtin_amdgcn_readfirstlane(tid >> 6);   // 0..3
    const int l   = tid & 63;
    const int ln  = l & 15;
    const int lq  = l >> 4;
    const int bb  = blockIdx.x;          // row 0..511

    const short* wpP1 = wpack;
    const short* wpCv = wpack + 4096;
    const short* wpWo = wpack + 40960;
    const short* wpO1 = wpack + 53248;
    const short* wpO2 = wpack + 54272;

    const int m2 = wv >> 1;              // P1 / o1 m-tile
    const int nn = wv & 1;               // P1 / conv / o1 n-tile
    const int colw = nn * 16 + ln;       // this wave's column for 2x2-tiled phases
    const bool cvw = (colw < 24);

    // ---- hoisted step-invariant A-frags ----
    bf16x8 aP1[4], aO1, aO2[2];
#pragma unroll
    for (int ks = 0; ks < 4; ++ks) aP1[ks] = ldfrag(wpP1 + (m2 * 4 + ks) * 512 + l * 8);
    aO1 = ldfrag(wpO1 + m2 * 512 + l * 8);
    aO2[0] = ldfrag(wpO2 + wv * 512 + l * 8);
    aO2[1] = ldfrag(wpO2 + (wv + 4) * 512 + l * 8);

    // ---- init ----
    for (int i = tid; i < 3072; i += 256) {
        int d = i / 24, h = i - d * 24;
        float v = z_init[(size_t)bb * 3072 + i];
        xsf[h * 132 + d] = v;
        xbB[h * 136 + d] = (short)rne1(v);
    }
    for (int i = tid; i < 8 * 136; i += 256) xbB[24 * 136 + i] = 0;   // pad rows
    if (tid < 40) hcB[32 * 40 + tid] = 0;                             // zero col
    for (int i = tid; i < 480; i += 256) reinterpret_cast<unsigned*>(skB)[i] = 0u;
    __syncthreads();

    for (int step = 0; step < T_STEPS; ++step) {
        const int t = T_STEPS - 1 - step;
        const float* cndt = cond_all + t * 192;

        // ---- noise: issue coalesced loads (12 KB contiguous, 3x float4/thread) ----
        float4 nzl0, nzl1, nzl2;
        {
            const float* nzb = noise + ((size_t)step * NB + bb) * 3072;
            nzl0 = ld4g(nzb + 0 * 1024 + tid * 4);
            nzl1 = ld4g(nzb + 1 * 1024 + tid * 4);
            nzl2 = ld4g(nzb + 2 * 1024 + tid * 4);
        }

        // ======== P1: h = relu(Win @ x + b_in) ========
        {
            f32x4 acc = bias4(b_in + m2 * 16 + lq * 4);
            const short* xb = xbB + colw * 136 + lq * 8;
#pragma unroll
            for (int ks = 0; ks < 4; ++ks)
                acc = mma(aP1[ks], ldfrag(xb + ks * 32), acc);
            if (cvw) {
                float4 cv = ld4g(cndt + m2 * 16 + lq * 4);
                float h0 = fmaxf(acc[0], 0.f), h1 = fmaxf(acc[1], 0.f);
                float h2 = fmaxf(acc[2], 0.f), h3 = fmaxf(acc[3], 0.f);
                st_bf4(hB + colw * 40 + m2 * 16 + lq * 4, h0, h1, h2, h3);
                st_bf4(hcB + colw * 40 + m2 * 16 + lq * 4,
                       h0 + cv.x, h1 + cv.y, h2 + cv.z, h3 + cv.w);
            }
            // noise -> LDS (write-late half of the async split; published by the barrier)
            st4s(nzB + 0 * 1024 + tid * 4, nzl0);
            st4s(nzB + 1 * 1024 + tid * 4, nzl1);
            st4s(nzB + 2 * 1024 + tid * 4, nzl2);
        }
        __syncthreads();

        // ======== 6 residual layers ========
#pragma unroll
        for (int li = 0; li < 6; ++li) {
            const int d = 1 << li;
            // ---- conv (3 shifted K=32 GEMMs) + gated act ----
            {
                const int mg = m2;
                f32x4 accg = bias4(lyr_bdil + li * 64 + mg * 16 + lq * 4);
                f32x4 accf = bias4(lyr_bdil + li * 64 + 32 + mg * 16 + lq * 4);
                const short* wc = wpCv + (li * 12 + mg * 6) * 512 + l * 8;
#pragma unroll
                for (int tp = 0; tp < 3; ++tp) {
                    if (li == 5 && tp != 1) continue;
                    int hh = colw + (tp - 1) * d;
                    int colp = ((unsigned)hh < 24u) ? hh : 32;
                    bf16x8 b = ldfrag(hcB + colp * 40 + lq * 8);
                    accg = mma(ldfrag(wc + (tp * 2 + 0) * 512), b, accg);
                    accf = mma(ldfrag(wc + (tp * 2 + 1) * 512), b, accf);
                }
                if (cvw)
                    st_bf4(actB + colw * 40 + mg * 16 + lq * 4,
                           fast_tanh(accf[0]) * fast_sig(accg[0]),
                           fast_tanh(accf[1]) * fast_sig(accg[1]),
                           fast_tanh(accf[2]) * fast_sig(accg[2]),
                           fast_tanh(accf[3]) * fast_sig(accg[3]));
            }
            __syncthreads();

            // ---- wout: 8 tiles (mo=wv, n=0..1) ----
            {
                const int mo = wv;
                bf16x8 a = ldfrag(wpWo + (li * 4 + mo) * 512 + l * 8);
                f32x4 bia = bias4(lyr_bout + li * 64 + mo * 16 + lq * 4);
#pragma unroll
                for (int n = 0; n < 2; ++n) {
                    const int col = n * 16 + ln;
                    f32x4 acc = mma(a, ldfrag(actB + col * 40 + lq * 8), bia);
                    if (col < 24) {
                        if (mo < 2) {
                            short* hp = hB + col * 40 + mo * 16 + lq * 4;
                            uint2 hv = *reinterpret_cast<uint2*>(hp);
                            float n0 = (bf2f(hv.x & 0xFFFFu) + acc[0]) * RS2;
                            float n1 = (bf2f(hv.x >> 16)     + acc[1]) * RS2;
                            float n2 = (bf2f(hv.y & 0xFFFFu) + acc[2]) * RS2;
                            float n3 = (bf2f(hv.y >> 16)     + acc[3]) * RS2;
                            st_bf4(hp, n0, n1, n2, n3);
                            if (li < 5) {
                                float4 cv = ld4g(cndt + (li + 1) * 32 + mo * 16 + lq * 4);
                                st_bf4(hcB + col * 40 + mo * 16 + lq * 4,
                                       n0 + cv.x, n1 + cv.y, n2 + cv.z, n3 + cv.w);
                            }
                        } else {
                            short* sp = skB + col * 40 + (mo - 2) * 16 + lq * 4;
                            uint2 sv = *reinterpret_cast<uint2*>(sp);
                            st_bf4(sp,
                                   bf2f(sv.x & 0xFFFFu) + acc[0],
                                   bf2f(sv.x >> 16)     + acc[1],
                                   bf2f(sv.y & 0xFFFFu) + acc[2],
                                   bf2f(sv.y >> 16)     + acc[3]);
                        }
                    }
                }
            }
            __syncthreads();
        }

        // ======== o1: s = relu(b_o1 + Wo1s @ skip) -> actB ========
        {
            f32x4 acc = bias4(b_o1 + m2 * 16 + lq * 4);
            acc = mma(aO1, ldfrag(skB + colw * 40 + lq * 8), acc);
            if (cvw)
                st_bf4(actB + colw * 40 + m2 * 16 + lq * 4,
                       fmaxf(acc[0], 0.f), fmaxf(acc[1], 0.f),
                       fmaxf(acc[2], 0.f), fmaxf(acc[3], 0.f));
        }
        __syncthreads();

        // ======== o2: eps + fused DDPM x-update; re-zero skB ========
        {
            const float cx0 = sc.cx0[t], cxt = sc.cxt[t], sig = sc.sig[t];
            const float s1m = sc.s1m[t], isab = sc.isab[t];
#pragma unroll
            for (int mi = 0; mi < 2; ++mi) {
                const int m8 = wv + 4 * mi;
                const int d0 = m8 * 16 + lq * 4;
                f32x4 bia = bias4(b_o2 + d0);
#pragma unroll
                for (int n = 0; n < 2; ++n) {
                    const int col = n * 16 + ln;
                    f32x4 acc = mma(aO2[mi], ldfrag(actB + col * 40 + lq * 8), bia);
                    if (col < 24) {
                        float* xp = xsf + col * 132 + d0;
                        float4 xv = ld4s(xp);
                        float4 rr;
#pragma unroll
                        for (int i = 0; i < 4; ++i) {
                            float xvv = (&xv.x)[i];
                            float nz = nzB[(d0 + i) * 24 + col];
                            float x0 = fminf(fmaxf((xvv - s1m * acc[i]) * isab, -1.f), 1.f);
                            (&rr.x)[i] = cx0 * x0 + cxt * xvv + sig * nz;
                        }
                        st4s(xp, rr);
                        st_bf4(xbB + col * 136 + d0, rr.x, rr.y, rr.z, rr.w);
                    }
                }
            }
            for (int i = tid; i < 480; i += 256) reinterpret_cast<unsigned*>(skB)[i] = 0u;
        }
        __syncthreads();
    }

    // ---- epilogue: Gaussian -> Student-t4, coalesced writes ----
    {
        const int b = bb & 31;
        for (int i = tid; i < 768; i += 256) {
            int col = i >> 5, q = i & 31;
            float4 zv = ld4s(xsf + col * 132 + q * 4);
            float4 l4 = ld4g(loc + b * 128 + q * 4);
            float4 s4 = ld4g(scalef + b * 128 + q * 4);
            float4 o4;
#pragma unroll
            for (int e = 0; e < 4; ++e) {
                float u = 0.5f * (1.f + erff((&zv.x)[e] * RS2));
                u = fminf(fmaxf(u, 1e-6f), 1.f - 1e-6f);
                float a4 = fminf(fmaxf(4.f * u * (1.f - u), 1e-12f), 1.f);
                float rr = sqrtf(a4);
                float q2 = 2.f * sqrtf(fmaxf(cosf(acosf(rr) * (1.f / 3.f)) / rr - 1.f, 0.f));
                float tstd = (u < 0.5f) ? -q2 : q2;
                (&o4.x)[e] = (&l4.x)[e] + (&s4.x)[e] * tstd;
            }
            *reinterpret_cast<float4*>(out + ((size_t)bb * 24 + col) * 128 + q * 4) = o4;
        }
    }
}

// ---------------- host ----------------
extern "C" void kernel_launch(void* const* d_in, const int* in_sizes, int n_in,
                              void* d_out, int out_size, void* d_ws, size_t ws_size,
                              hipStream_t stream) {
    const float* x_hist  = (const float*)d_in[0];
    const float* z_init  = (const float*)d_in[1];
    const float* noise   = (const float*)d_in[2];
    const float* w_in    = (const float*)d_in[3];
    const float* b_in    = (const float*)d_in[4];
    const float* temb_w1 = (const float*)d_in[5];
    const float* temb_b1 = (const float*)d_in[6];
    const float* temb_w2 = (const float*)d_in[7];
    const float* temb_b2 = (const float*)d_in[8];
    const float* lyr_wt  = (const float*)d_in[9];
    const float* lyr_bt  = (const float*)d_in[10];
    const float* lyr_wdil= (const float*)d_in[11];
    const float* lyr_bdil= (const float*)d_in[12];
    const float* lyr_wout= (const float*)d_in[13];
    const float* lyr_bout= (const float*)d_in[14];
    const float* w_o1    = (const float*)d_in[15];
    const float* b_o1    = (const float*)d_in[16];
    const float* w_o2    = (const float*)d_in[17];
    const float* b_o2    = (const float*)d_in[18];
    float* out = (float*)d_out;

    float* loc      = (float*)d_ws;                     // 4096 f32
    float* scalef   = loc + 4096;                       // 4096 f32
    float* cond_all = scalef + 4096;                    // 9600 f32
    short* wpack    = (short*)d_ws + WPACK_SHORT_OFF;   // 58368 bf16

    SchedArg sa;
    double abar = 1.0;
    for (int t = 0; t < T_STEPS; ++t) {
        double beta  = 1e-4 + (0.1 - 1e-4) * ((double)t / 49.0);
        double alpha = 1.0 - beta;
        double abprev = abar;
        abar *= alpha;
        sa.cx0[t]  = (float)(beta * sqrt(abprev) / (1.0 - abar));
        sa.cxt[t]  = (float)((1.0 - abprev) * sqrt(alpha) / (1.0 - abar));
        double pv  = beta * (1.0 - abprev) / (1.0 - abar);
        sa.sig[t]  = (t > 0) ? (float)sqrt(pv) : 0.f;
        sa.s1m[t]  = (float)sqrt(1.0 - abar);
        sa.isab[t] = (float)(1.0 / sqrt(abar));
    }
    FreqArg fa;
    for (int j = 0; j < 64; ++j) fa.f[j] = pow(10.0, (double)j * 4.0 / 63.0);

    prep_kernel<<<228, 256, 0, stream>>>(w_in, lyr_wdil, lyr_wout, w_o1, w_o2, wpack);
    fit_kernel<<<16, 256, 0, stream>>>(x_hist, loc, scalef);
    temb_kernel<<<T_STEPS, 256, 0, stream>>>(temb_w1, temb_b1, temb_w2, temb_b2,
                                             lyr_wt, lyr_bt, cond_all, fa);
    diffusion_kernel<<<NB, 256, 0, stream>>>(z_init, noise, b_in, lyr_bdil,
                                             lyr_bout, b_o1, b_o2, cond_all,
                                             wpack, loc, scalef, out, sa);
}